// Round 17
// baseline (2009.035 us; speedup 1.0000x reference)
//
#include <hip/hip_runtime.h>
#include <hip/hip_bf16.h>

// ---------------------------------------------------------------------------
// StateSpaceLite on MI355X.
//   u = x@W_in^T + b_in            (bf16 MFMA GEMM -> d_out, in place)
//   scan over t: driven = tanh(u_t + s@W_state^T + b_state)
//                s' = d*s + (1-d)*driven ; y_t = LN(s')*gamma + beta
// Round-17: fused tagged protocol (r14/r16) rebuilt with:
//  (1) RAW s_barrier + targeted lgkmcnt in the loop (no compiler vmcnt(0)
//      drains - __syncthreads emits them; raw barriers don't),
//  (2) ALL in-loop global ops as volatile asm with FIXED issue order
//      {publish4, u4, twA16, y4(dummy for t<2), ..., twB16} so the next
//      iteration's s_waitcnt vmcnt(20) covers exactly publish+u+twA,
//  (3) TWO-STAGE speculation: twA issued early (fully hidden), twB issued
//      late (fresher); check A, then B, then retry loop. Converts the
//      common stale-retry round trip into a short or zero wait.
// Tagged word = (tag16<<16)|bf16; triple buffer; fence-free sc0sc1 reads;
// 4 groups x 16 blocks; W slice in LDS.
// ---------------------------------------------------------------------------

#define B_    64
#define T_    512
#define H_    1024
#define GCOLS 64

typedef __attribute__((ext_vector_type(8))) __bf16 bf16x8;
typedef __attribute__((ext_vector_type(4))) float f32x4;
typedef __attribute__((ext_vector_type(4))) unsigned uint32x4;

static __device__ __forceinline__ unsigned f2bf_bits(float f) {
    unsigned u = __float_as_uint(f);
    return (u + 0x7FFFu + ((u >> 16) & 1u)) >> 16;   // RNE, finite inputs
}

static __device__ __forceinline__ float fast_tanh(float x) {
    x = fminf(fmaxf(x, -15.f), 15.f);
    const float e = __expf(2.f * x);                  // finite after clamp
    return 1.f - 2.f * __builtin_amdgcn_rcpf(e + 1.f);
}

// direct-to-IC load (bypass L1+L2): always observes the coherence point
#define SLOADC(dst, base, BOFF)                                               \
    asm volatile("global_load_dwordx4 %0, %1, off offset:%2 sc0 sc1"          \
                 : "=&v"(dst) : "v"(base), "n"(BOFF))
#define ULOAD(dst, base)                                                      \
    asm volatile("global_load_dword %0, %1, off"                              \
                 : "=&v"(dst) : "v"(base))
#define PSTORE(base, data)                                                    \
    asm volatile("global_store_dword %0, %1, off sc0 sc1"                     \
                 :: "v"(base), "v"(data))
#define YSTORE(base, data)                                                    \
    asm volatile("global_store_dword %0, %1, off" :: "v"(base), "v"(data))
#define VMCNT20() asm volatile("s_waitcnt vmcnt(20)" ::: "memory")
#define VMCNT0()  asm volatile("s_waitcnt vmcnt(0)" ::: "memory")
#define LGKM0()   asm volatile("s_waitcnt lgkmcnt(0)" ::: "memory")
#define SBAR()    __builtin_amdgcn_s_barrier()
#define SCHEDB()  __builtin_amdgcn_sched_barrier(0)

// ------------------------------- u GEMM ------------------------------------
#define BM 128
#define BN 128
#define BKK 32
#define LDT 40

__global__ __launch_bounds__(256)
void u_gemm(const float* __restrict__ X, const float* __restrict__ Win,
            const float* __restrict__ bin, float* __restrict__ U) {
    __shared__ unsigned short Al[BM][LDT];
    __shared__ unsigned short Bl[BN][LDT];
    const int tid = threadIdx.x;
    const int m0 = blockIdx.y * BM;
    const int n0 = blockIdx.x * BN;
    const int l  = tid & 63;
    const int w  = tid >> 6;
    const int wr = (w >> 1) * 64, wc = (w & 1) * 64;
    const int fr = l & 15, fk = (l >> 4) * 8;

    f32x4 acc[4][4];
#pragma unroll
    for (int m = 0; m < 4; ++m)
#pragma unroll
        for (int n = 0; n < 4; ++n) acc[m][n] = f32x4{0.f, 0.f, 0.f, 0.f};

    const int sr = tid >> 1;
    const int sc = (tid & 1) * 16;

    for (int k0 = 0; k0 < 512; k0 += BKK) {
        const float* ap = X   + (size_t)(m0 + sr) * 512 + k0 + sc;
        const float* bp = Win + (size_t)(n0 + sr) * 512 + k0 + sc;
        float a[16], b[16];
#pragma unroll
        for (int j = 0; j < 4; ++j) {
            *(float4*)&a[j * 4] = *(const float4*)(ap + j * 4);
            *(float4*)&b[j * 4] = *(const float4*)(bp + j * 4);
        }
        __syncthreads();
#pragma unroll
        for (int j = 0; j < 16; ++j) {
            Al[sr][sc + j] = (unsigned short)f2bf_bits(a[j]);
            Bl[sr][sc + j] = (unsigned short)f2bf_bits(b[j]);
        }
        __syncthreads();

        bf16x8 af[4], bf[4];
#pragma unroll
        for (int m = 0; m < 4; ++m)
            af[m] = *(const bf16x8*)&Al[wr + m * 16 + fr][fk];
#pragma unroll
        for (int n = 0; n < 4; ++n)
            bf[n] = *(const bf16x8*)&Bl[wc + n * 16 + fr][fk];
#pragma unroll
        for (int m = 0; m < 4; ++m)
#pragma unroll
            for (int n = 0; n < 4; ++n)
                acc[m][n] = __builtin_amdgcn_mfma_f32_16x16x32_bf16(
                    af[m], bf[n], acc[m][n], 0, 0, 0);
    }

#pragma unroll
    for (int m = 0; m < 4; ++m) {
#pragma unroll
        for (int n = 0; n < 4; ++n) {
            const int col = n0 + wc + n * 16 + fr;
            const float bb = bin[col];
#pragma unroll
            for (int r = 0; r < 4; ++r) {
                const int row = m0 + wr + m * 16 + (l >> 4) * 4 + r;
                U[(size_t)row * 1024 + col] = acc[m][n][r] + bb;
            }
        }
    }
}

// ----------------------------- recurrence ----------------------------------
__global__ __launch_bounds__(256, 1)
void rec_tag4(const float* __restrict__ Wst, float* __restrict__ UY,
              const float* __restrict__ b_state, const float* __restrict__ decay,
              const float* __restrict__ gamma, const float* __restrict__ beta,
              unsigned* __restrict__ Sbuf, unsigned* __restrict__ ydump) {
    extern __shared__ __align__(16) unsigned char smem[];
    unsigned short* Wl = (unsigned short*)smem;           // [128][64][8] 128 KB
    unsigned*       Sl = (unsigned*)(smem + 131072);      // [16][512] swizzled 32 KB
    float*          muS = (float*)(smem + 131072);        // overlays Sl (post-MFMA)
    float*          rsS = muS + 16;

    const int tid  = threadIdx.x;
    const int bid  = blockIdx.x;
    const int rg   = bid >> 4;
    const int cbk  = bid & 15;
    const int h0   = cbk * GCOLS;
    const int wave = tid >> 6;
    const int lane = tid & 63;
    const int c    = lane & 15;
    const int rgrp = lane >> 4;
    const int mycol = h0 + wave * 16 + c;
    const int lrow  = wave * 4 + rgrp;

    // ---- W slice (64 cols x 1024) -> LDS bf16, once ----
    {
        const int col = tid >> 2;
        const int sub = tid & 3;
        const float* wr_ = Wst + (size_t)(h0 + col) * H_ + sub * 256;
#pragma unroll
        for (int i = 0; i < 32; ++i) {
            float4 f0 = *(const float4*)(wr_ + i * 8);
            float4 f1 = *(const float4*)(wr_ + i * 8 + 4);
            unsigned short* dst = Wl + ((size_t)(sub * 32 + i) * 64 + col) * 8;
            dst[0] = (unsigned short)f2bf_bits(f0.x);
            dst[1] = (unsigned short)f2bf_bits(f0.y);
            dst[2] = (unsigned short)f2bf_bits(f0.z);
            dst[3] = (unsigned short)f2bf_bits(f0.w);
            dst[4] = (unsigned short)f2bf_bits(f1.x);
            dst[5] = (unsigned short)f2bf_bits(f1.y);
            dst[6] = (unsigned short)f2bf_bits(f1.z);
            dst[7] = (unsigned short)f2bf_bits(f1.w);
        }
    }

    const float d_c  = 1.f / (1.f + __expf(-decay[mycol]));
    const float od_c = 1.f - d_c;
    const float bs_c = b_state[mycol];
    const float g_c  = gamma[mycol];
    const float be_c = beta[mycol];

    float sold[4] = {0.f, 0.f, 0.f, 0.f};
    int brow[4];
#pragma unroll
    for (int r = 0; r < 4; ++r) brow[r] = rg * 16 + rgrp * 4 + r;

    float yv[4] = {0.f, 0.f, 0.f, 0.f};
    unsigned* const Sg = Sbuf + ((size_t)rg * 3 << 14);   // 3 x [16][1024] u32
    const int swzW = (lrow & 7) << 2;
    const int swzR = (c & 7) << 2;
    unsigned* const yd = ydump + (bid << 8) + tid;

    __syncthreads();   // full drain: all compiler VM ops (W stage, params) done

    // ---- prologue mirrors the per-iter tail op shape (counts constant) ----
    uint32x4 twA[16], twB[16];
    float uun[4], uu[4];
    {
#pragma unroll
        for (int r = 0; r < 4; ++r) {
            const float* ub = UY + (size_t)brow[r] * T_ * H_ + mycol;
            ULOAD(uun[r], ub);
        }
        const unsigned* lb0 = Sg + (size_t)lrow * 1024 + c * 4;
#pragma unroll
        for (int j = 0; j < 16; ++j) SLOADC(twA[j], lb0, j * 256);
#pragma unroll
        for (int r = 0; r < 4; ++r) YSTORE(yd, 0u);
#pragma unroll
        for (int j = 0; j < 16; ++j) SLOADC(twB[j], lb0, j * 256);
    }

    for (int t = 0; t < T_; ++t) {
        unsigned*       Sw = Sg + ((size_t)((t + 1) % 3) << 14);
        const unsigned tagr = (unsigned)t, tagw = (unsigned)(t + 1);
        const unsigned* lb =
            Sg + ((size_t)(t % 3) << 14) + (size_t)lrow * 1024 + c * 4;

        SBAR();                 // (A) raw: LDS epoch boundary, NO vmcnt drain
        VMCNT20(); SCHEDB();    // publish+u+twA complete (y, twB still flying)
#pragma unroll
        for (int r = 0; r < 4; ++r) uu[r] = uun[r];

        // ==== two-stage freshness check ====
        {
            unsigned mn = 0xFFFFFFFFu;
#pragma unroll
            for (int j = 0; j < 16; ++j) {
                unsigned m01 = twA[j][0] < twA[j][1] ? twA[j][0] : twA[j][1];
                unsigned m23 = twA[j][2] < twA[j][3] ? twA[j][2] : twA[j][3];
                unsigned m = m01 < m23 ? m01 : m23;
                mn = mn < m ? mn : m;
            }
            if (!__all((mn >> 16) == tagr)) {
                VMCNT0(); SCHEDB();              // twB (late, fresher) arrived
                unsigned mb = 0xFFFFFFFFu;
#pragma unroll
                for (int j = 0; j < 16; ++j) {
                    unsigned m01 = twB[j][0] < twB[j][1] ? twB[j][0] : twB[j][1];
                    unsigned m23 = twB[j][2] < twB[j][3] ? twB[j][2] : twB[j][3];
                    unsigned m = m01 < m23 ? m01 : m23;
                    mb = mb < m ? mb : m;
                }
                if (__all((mb >> 16) == tagr)) {
#pragma unroll
                    for (int j = 0; j < 16; ++j) twA[j] = twB[j];
                } else {
                    int spin = 0;
                    for (;;) {
                        if ((spin & 7) == 7)
                            __builtin_amdgcn_fence(__ATOMIC_ACQUIRE, "agent");
                        ++spin;
                        __builtin_amdgcn_s_sleep(1);
#pragma unroll
                        for (int j = 0; j < 16; ++j) SLOADC(twA[j], lb, j * 256);
                        VMCNT0(); SCHEDB();
                        unsigned m2 = 0xFFFFFFFFu;
#pragma unroll
                        for (int j = 0; j < 16; ++j) {
                            unsigned m01 = twA[j][0] < twA[j][1] ? twA[j][0] : twA[j][1];
                            unsigned m23 = twA[j][2] < twA[j][3] ? twA[j][2] : twA[j][3];
                            unsigned m = m01 < m23 ? m01 : m23;
                            m2 = m2 < m ? m2 : m;
                        }
                        if (__all((m2 >> 16) == tagr)) break;
                    }
                }
            }
        }

        // ==== LN partial stats of row lrow ====
        float s1 = 0.f, s2 = 0.f;
#pragma unroll
        for (int j = 0; j < 16; ++j) {
#pragma unroll
            for (int k = 0; k < 4; ++k) {
                const float v = __uint_as_float(twA[j][k] << 16);
                s1 += v;
                s2 = fmaf(v, v, s2);
            }
        }
        s1 += __shfl_xor(s1, 1); s2 += __shfl_xor(s2, 1);
        s1 += __shfl_xor(s1, 2); s2 += __shfl_xor(s2, 2);
        s1 += __shfl_xor(s1, 4); s2 += __shfl_xor(s2, 4);
        s1 += __shfl_xor(s1, 8); s2 += __shfl_xor(s2, 8);
        const float mu_l = s1 * (1.f / (float)H_);
        const float rs_l = rsqrtf(s2 * (1.f / (float)H_) - mu_l * mu_l + 1e-5f);

        // ==== repack to bf16 pairs, share via swizzled LDS ====
#pragma unroll
        for (int j = 0; j < 16; ++j) {
            const unsigned p0 = __builtin_amdgcn_perm(twA[j][1], twA[j][0], 0x05040100u);
            const unsigned p1 = __builtin_amdgcn_perm(twA[j][3], twA[j][2], 0x05040100u);
            const int idx = (j * 32 + c * 2) ^ swzW;
            *(uint2*)&Sl[lrow * 512 + idx] = uint2{p0, p1};
        }
        LGKM0(); SBAR();   // (B) writes visible, raw barrier

        // ==== MFMA from LDS: acc = s_t @ Wslice^T ====
        f32x4 a0 = {0.f, 0.f, 0.f, 0.f}, a1 = a0, a2 = a0, a3 = a0;
#pragma unroll
        for (int kk = 0; kk < 32; kk += 4) {
#pragma unroll
            for (int q = 0; q < 4; ++q) {
                const int ai = ((kk + q) * 16 + rgrp * 4) ^ swzR;
                const uint32x4 aw = *(const uint32x4*)&Sl[c * 512 + ai];
                const bf16x8 af = __builtin_bit_cast(bf16x8, aw);
                const bf16x8 bf = *(const bf16x8*)(Wl +
                    ((size_t)((kk + q) * 4 + rgrp) * 64 + wave * 16 + c) * 8);
                if (q == 0) a0 = __builtin_amdgcn_mfma_f32_16x16x32_bf16(af, bf, a0, 0, 0, 0);
                if (q == 1) a1 = __builtin_amdgcn_mfma_f32_16x16x32_bf16(af, bf, a1, 0, 0, 0);
                if (q == 2) a2 = __builtin_amdgcn_mfma_f32_16x16x32_bf16(af, bf, a2, 0, 0, 0);
                if (q == 3) a3 = __builtin_amdgcn_mfma_f32_16x16x32_bf16(af, bf, a3, 0, 0, 0);
            }
        }
        const f32x4 acc = (a0 + a1) + (a2 + a3);

        // ==== update + publish (VM op order: publish4, u4, twA16, y4) ====
        float sprev[4];
#pragma unroll
        for (int r = 0; r < 4; ++r) {
            sprev[r] = sold[r];
            const float pre = acc[r] + uu[r] + bs_c;
            const float sn  = d_c * sold[r] + od_c * fast_tanh(pre);
            sold[r] = sn;
            unsigned* pa = &Sw[(size_t)(rgrp * 4 + r) * 1024 + mycol];
            const unsigned pd = (tagw << 16) | f2bf_bits(sn);
            PSTORE(pa, pd);
        }
        {
            const int tn = (t + 1 < T_) ? (t + 1) : (T_ - 1);
#pragma unroll
            for (int r = 0; r < 4; ++r) {
                const float* ub = UY + ((size_t)brow[r] * T_ + tn) * H_ + mycol;
                ULOAD(uun[r], ub);
            }
        }
        const unsigned* lbn =
            Sg + ((size_t)((t + 1) % 3) << 14) + (size_t)lrow * 1024 + c * 4;
#pragma unroll
        for (int j = 0; j < 16; ++j) SLOADC(twA[j], lbn, j * 256);   // early spec
        if (t >= 2) {
#pragma unroll
            for (int r = 0; r < 4; ++r) {
                float* yt = UY + ((size_t)brow[r] * T_ + (t - 2)) * H_ + mycol;
                YSTORE(yt, __float_as_uint(yv[r]));
            }
        } else {
#pragma unroll
            for (int r = 0; r < 4; ++r) YSTORE(yd, 0u);
        }

        // ==== shadow: stats exchange + yv; then late spec twB ====
        SBAR();             // (C) MFMA Sl reads done (muS overlays Sl)
        if (c == 0) { muS[lrow] = mu_l; rsS[lrow] = rs_l; }
        LGKM0(); SBAR();    // (D)
#pragma unroll
        for (int r = 0; r < 4; ++r) {
            const int R = rgrp * 4 + r;
            yv[r] = (sprev[r] - muS[R]) * rsS[R] * g_c + be_c;
        }
#pragma unroll
        for (int j = 0; j < 16; ++j) SLOADC(twB[j], lbn, j * 256);   // late spec
    }

    // ==== epilogue: store y_510; then y_511 = LN(s_512) ====
    {
        VMCNT0(); SCHEDB();   // everything drained (incl. last twA/twB)
#pragma unroll
        for (int r = 0; r < 4; ++r) {
            float* yt = UY + ((size_t)brow[r] * T_ + (T_ - 2)) * H_ + mycol;
            YSTORE(yt, __float_as_uint(yv[r]));
        }
        const unsigned tagr = (unsigned)T_;
        const unsigned* lb =
            Sg + ((size_t)(T_ % 3) << 14) + (size_t)lrow * 1024 + c * 4;
        // twA/twB already hold buf[T_%3] loads from the last tail
        unsigned mn = 0xFFFFFFFFu;
#pragma unroll
        for (int j = 0; j < 16; ++j) {
            unsigned m01 = twA[j][0] < twA[j][1] ? twA[j][0] : twA[j][1];
            unsigned m23 = twA[j][2] < twA[j][3] ? twA[j][2] : twA[j][3];
            unsigned m = m01 < m23 ? m01 : m23;
            mn = mn < m ? mn : m;
        }
        if (!__all((mn >> 16) == tagr)) {
            unsigned mb = 0xFFFFFFFFu;
#pragma unroll
            for (int j = 0; j < 16; ++j) {
                unsigned m01 = twB[j][0] < twB[j][1] ? twB[j][0] : twB[j][1];
                unsigned m23 = twB[j][2] < twB[j][3] ? twB[j][2] : twB[j][3];
                unsigned m = m01 < m23 ? m01 : m23;
                mb = mb < m ? mb : m;
            }
            if (__all((mb >> 16) == tagr)) {
#pragma unroll
                for (int j = 0; j < 16; ++j) twA[j] = twB[j];
            } else {
                int spin = 0;
                for (;;) {
                    if ((spin & 7) == 7)
                        __builtin_amdgcn_fence(__ATOMIC_ACQUIRE, "agent");
                    ++spin;
                    __builtin_amdgcn_s_sleep(1);
#pragma unroll
                    for (int j = 0; j < 16; ++j) SLOADC(twA[j], lb, j * 256);
                    VMCNT0(); SCHEDB();
                    unsigned m2 = 0xFFFFFFFFu;
#pragma unroll
                    for (int j = 0; j < 16; ++j) {
                        unsigned m01 = twA[j][0] < twA[j][1] ? twA[j][0] : twA[j][1];
                        unsigned m23 = twA[j][2] < twA[j][3] ? twA[j][2] : twA[j][3];
                        unsigned m = m01 < m23 ? m01 : m23;
                        m2 = m2 < m ? m2 : m;
                    }
                    if (__all((m2 >> 16) == tagr)) break;
                }
            }
        }
        float s1 = 0.f, s2 = 0.f;
#pragma unroll
        for (int j = 0; j < 16; ++j) {
#pragma unroll
            for (int k = 0; k < 4; ++k) {
                const float v = __uint_as_float(twA[j][k] << 16);
                s1 += v;
                s2 = fmaf(v, v, s2);
            }
        }
        s1 += __shfl_xor(s1, 1); s2 += __shfl_xor(s2, 1);
        s1 += __shfl_xor(s1, 2); s2 += __shfl_xor(s2, 2);
        s1 += __shfl_xor(s1, 4); s2 += __shfl_xor(s2, 4);
        s1 += __shfl_xor(s1, 8); s2 += __shfl_xor(s2, 8);
        const float mu_l = s1 * (1.f / (float)H_);
        const float rs_l = rsqrtf(s2 * (1.f / (float)H_) - mu_l * mu_l + 1e-5f);
        __syncthreads();                      // full barrier OK outside loop
        if (c == 0) { muS[lrow] = mu_l; rsS[lrow] = rs_l; }
        __syncthreads();
#pragma unroll
        for (int r = 0; r < 4; ++r) {
            const int R = rgrp * 4 + r;
            UY[((size_t)brow[r] * T_ + (T_ - 1)) * H_ + mycol] =
                (sold[r] - muS[R]) * rsS[R] * g_c + be_c;
        }
    }
}

// ---------------------------------------------------------------------------
extern "C" void kernel_launch(void* const* d_in, const int* in_sizes, int n_in,
                              void* d_out, int out_size, void* d_ws, size_t ws_size,
                              hipStream_t stream) {
    const float* x   = (const float*)d_in[0];
    const float* Win = (const float*)d_in[1];
    const float* bin = (const float*)d_in[2];
    const float* Wst = (const float*)d_in[3];
    const float* bst = (const float*)d_in[4];
    const float* dec = (const float*)d_in[5];
    const float* lng = (const float*)d_in[6];
    const float* lnb = (const float*)d_in[7];
    float* out = (float*)d_out;

    unsigned char* ws = (unsigned char*)d_ws;
    unsigned* Sbuf  = (unsigned*)(ws + 4096);            // 4 grp x 3 x 64KB
    unsigned* ydump = (unsigned*)(ws + 4096 + 786432);   // 64 KB dummy-store sink

    hipFuncSetAttribute(reinterpret_cast<const void*>(rec_tag4),
                        hipFuncAttributeMaxDynamicSharedMemorySize, 163840);

    hipMemsetAsync(Sbuf, 0, 4u * 3u * 16u * 1024u * 4u, stream);  // tag0 = s_0
    u_gemm<<<dim3(8, 256), 256, 0, stream>>>(x, Win, bin, out);
    rec_tag4<<<64, 256, 163840, stream>>>(Wst, out, bst, dec, lng, lnb,
                                          Sbuf, ydump);
}

// Round 18
// 1654.387 us; speedup vs baseline: 1.2144x; 1.2144x over previous
//
#include <hip/hip_runtime.h>
#include <hip/hip_bf16.h>

// ---------------------------------------------------------------------------
// StateSpaceLite on MI355X.
//   u = x@W_in^T + b_in            (bf16 MFMA GEMM -> d_out, in place)
//   scan over t: driven = tanh(u_t + s@W_state^T + b_state)
//                s' = d*s + (1-d)*driven ; y_t = LN(s')*gamma + beta
// Round-18 = Round-16 verbatim (proven best: 1.656 ms total, absmax 0.0156).
// Fused tagged protocol: state word = (tag16<<16)|bf16, triple-buffered;
// fence-free sc0sc1 direct-IC reads; speculative early issue of the next
// step's tagged loads in the shadow phase; counted first wait vmcnt(4).
// 4 groups x 16 blocks; W slice (64x1024 bf16) in LDS.
// ---------------------------------------------------------------------------

#define B_    64
#define T_    512
#define H_    1024
#define GCOLS 64

typedef __attribute__((ext_vector_type(8))) __bf16 bf16x8;
typedef __attribute__((ext_vector_type(4))) float f32x4;
typedef __attribute__((ext_vector_type(4))) unsigned uint32x4;

static __device__ __forceinline__ unsigned f2bf_bits(float f) {
    unsigned u = __float_as_uint(f);
    return (u + 0x7FFFu + ((u >> 16) & 1u)) >> 16;   // RNE, finite inputs
}

static __device__ __forceinline__ float fast_tanh(float x) {
    x = fminf(fmaxf(x, -15.f), 15.f);
    const float e = __expf(2.f * x);                  // finite after clamp
    return 1.f - 2.f * __builtin_amdgcn_rcpf(e + 1.f);
}

// direct-to-IC load (bypass L1+L2): always observes the coherence point
#define SLOADC(dst, base, BOFF)                                               \
    asm volatile("global_load_dwordx4 %0, %1, off offset:%2 sc0 sc1"          \
                 : "=&v"(dst) : "v"(base), "n"(BOFF))
#define ULOAD(dst, base)                                                      \
    asm volatile("global_load_dword %0, %1, off"                              \
                 : "=&v"(dst) : "v"(base))

// ------------------------------- u GEMM ------------------------------------
#define BM 128
#define BN 128
#define BKK 32
#define LDT 40

__global__ __launch_bounds__(256)
void u_gemm(const float* __restrict__ X, const float* __restrict__ Win,
            const float* __restrict__ bin, float* __restrict__ U) {
    __shared__ unsigned short Al[BM][LDT];
    __shared__ unsigned short Bl[BN][LDT];
    const int tid = threadIdx.x;
    const int m0 = blockIdx.y * BM;
    const int n0 = blockIdx.x * BN;
    const int l  = tid & 63;
    const int w  = tid >> 6;
    const int wr = (w >> 1) * 64, wc = (w & 1) * 64;
    const int fr = l & 15, fk = (l >> 4) * 8;

    f32x4 acc[4][4];
#pragma unroll
    for (int m = 0; m < 4; ++m)
#pragma unroll
        for (int n = 0; n < 4; ++n) acc[m][n] = f32x4{0.f, 0.f, 0.f, 0.f};

    const int sr = tid >> 1;
    const int sc = (tid & 1) * 16;

    for (int k0 = 0; k0 < 512; k0 += BKK) {
        const float* ap = X   + (size_t)(m0 + sr) * 512 + k0 + sc;
        const float* bp = Win + (size_t)(n0 + sr) * 512 + k0 + sc;
        float a[16], b[16];
#pragma unroll
        for (int j = 0; j < 4; ++j) {
            *(float4*)&a[j * 4] = *(const float4*)(ap + j * 4);
            *(float4*)&b[j * 4] = *(const float4*)(bp + j * 4);
        }
        __syncthreads();
#pragma unroll
        for (int j = 0; j < 16; ++j) {
            Al[sr][sc + j] = (unsigned short)f2bf_bits(a[j]);
            Bl[sr][sc + j] = (unsigned short)f2bf_bits(b[j]);
        }
        __syncthreads();

        bf16x8 af[4], bf[4];
#pragma unroll
        for (int m = 0; m < 4; ++m)
            af[m] = *(const bf16x8*)&Al[wr + m * 16 + fr][fk];
#pragma unroll
        for (int n = 0; n < 4; ++n)
            bf[n] = *(const bf16x8*)&Bl[wc + n * 16 + fr][fk];
#pragma unroll
        for (int m = 0; m < 4; ++m)
#pragma unroll
            for (int n = 0; n < 4; ++n)
                acc[m][n] = __builtin_amdgcn_mfma_f32_16x16x32_bf16(
                    af[m], bf[n], acc[m][n], 0, 0, 0);
    }

#pragma unroll
    for (int m = 0; m < 4; ++m) {
#pragma unroll
        for (int n = 0; n < 4; ++n) {
            const int col = n0 + wc + n * 16 + fr;
            const float bb = bin[col];
#pragma unroll
            for (int r = 0; r < 4; ++r) {
                const int row = m0 + wr + m * 16 + (l >> 4) * 4 + r;
                U[(size_t)row * 1024 + col] = acc[m][n][r] + bb;
            }
        }
    }
}

// ----------------------------- recurrence ----------------------------------
__global__ __launch_bounds__(256, 1)
void rec_tag3(const float* __restrict__ Wst, float* __restrict__ UY,
              const float* __restrict__ b_state, const float* __restrict__ decay,
              const float* __restrict__ gamma, const float* __restrict__ beta,
              unsigned* __restrict__ Sbuf) {
    extern __shared__ __align__(16) unsigned char smem[];
    unsigned short* Wl = (unsigned short*)smem;           // [128][64][8] 128 KB
    unsigned*       Sl = (unsigned*)(smem + 131072);      // [16][512] swizzled 32 KB
    float*          muS = (float*)(smem + 131072);        // overlays Sl (post-MFMA)
    float*          rsS = muS + 16;

    const int tid  = threadIdx.x;
    const int bid  = blockIdx.x;
    const int rg   = bid >> 4;              // group 0..3 (16 batch rows each)
    const int cbk  = bid & 15;              // col block 0..15
    const int h0   = cbk * GCOLS;
    const int wave = tid >> 6;
    const int lane = tid & 63;
    const int c    = lane & 15;             // A-row / C-col / load col-cluster
    const int rgrp = lane >> 4;             // k-chunk / C-row group
    const int mycol = h0 + wave * 16 + c;
    const int lrow  = wave * 4 + rgrp;      // row this lane LOADS (0..15)

    // ---- W slice (64 cols x 1024) -> LDS bf16, once ----
    {
        const int col = tid >> 2;
        const int sub = tid & 3;
        const float* wr_ = Wst + (size_t)(h0 + col) * H_ + sub * 256;
#pragma unroll
        for (int i = 0; i < 32; ++i) {
            float4 f0 = *(const float4*)(wr_ + i * 8);
            float4 f1 = *(const float4*)(wr_ + i * 8 + 4);
            unsigned short* dst = Wl + ((size_t)(sub * 32 + i) * 64 + col) * 8;
            dst[0] = (unsigned short)f2bf_bits(f0.x);
            dst[1] = (unsigned short)f2bf_bits(f0.y);
            dst[2] = (unsigned short)f2bf_bits(f0.z);
            dst[3] = (unsigned short)f2bf_bits(f0.w);
            dst[4] = (unsigned short)f2bf_bits(f1.x);
            dst[5] = (unsigned short)f2bf_bits(f1.y);
            dst[6] = (unsigned short)f2bf_bits(f1.z);
            dst[7] = (unsigned short)f2bf_bits(f1.w);
        }
    }

    const float d_c  = 1.f / (1.f + __expf(-decay[mycol]));
    const float od_c = 1.f - d_c;
    const float bs_c = b_state[mycol];
    const float g_c  = gamma[mycol];
    const float be_c = beta[mycol];

    float sold[4] = {0.f, 0.f, 0.f, 0.f};
    int brow[4];
#pragma unroll
    for (int r = 0; r < 4; ++r) brow[r] = rg * 16 + rgrp * 4 + r;

    float yv[4] = {0.f, 0.f, 0.f, 0.f};
    float uun[4], uu[4];
#pragma unroll
    for (int r = 0; r < 4; ++r)
        uun[r] = UY[(size_t)brow[r] * T_ * H_ + mycol];   // u_0 (plain)

    unsigned* const Sg = Sbuf + ((size_t)rg * 3 << 14);   // 3 x [16][1024] u32
    const int swzW = (lrow & 7) << 2;
    const int swzR = (c & 7) << 2;

    // ---- prologue: issue S attempt-1 for t=0 (tag 0 via memset), drain ----
    uint32x4 tw[16];
    {
        const unsigned* lb0 = Sg + (size_t)lrow * 1024 + c * 4;  // buf 0
#pragma unroll
        for (int j = 0; j < 16; ++j) SLOADC(tw[j], lb0, j * 256);
        asm volatile("s_waitcnt vmcnt(0)" ::: "memory");
        __builtin_amdgcn_sched_barrier(0);
    }

    __syncthreads();

    for (int t = 0; t < T_; ++t) {
        const unsigned* Sr = Sg + ((size_t)(t % 3) << 14);
        unsigned*       Sw = Sg + ((size_t)((t + 1) % 3) << 14);
        const unsigned tagr = (unsigned)t, tagw = (unsigned)(t + 1);
        const unsigned* lb = Sr + (size_t)lrow * 1024 + c * 4;

        // ==== (A) prev yv muS-reads done before this iter's Sl writes ====
        __syncthreads();

        // ==== counted wait: u_t + S attempt-1 arrived (y stores excluded) ====
        asm volatile("s_waitcnt vmcnt(4)" ::: "memory");
        __builtin_amdgcn_sched_barrier(0);
#pragma unroll
        for (int r = 0; r < 4; ++r) uu[r] = uun[r];

        // ==== verify tags; fence-free retries (sc0sc1 reads IC truth) ====
        {
            int spin = 0;
            for (;;) {
                unsigned mn = 0xFFFFFFFFu;
#pragma unroll
                for (int j = 0; j < 16; ++j) {
                    unsigned m01 = tw[j][0] < tw[j][1] ? tw[j][0] : tw[j][1];
                    unsigned m23 = tw[j][2] < tw[j][3] ? tw[j][2] : tw[j][3];
                    unsigned m = m01 < m23 ? m01 : m23;
                    mn = mn < m ? mn : m;
                }
                if (__all((mn >> 16) == tagr)) break;
                if (((++spin) & 7) == 7)
                    __builtin_amdgcn_fence(__ATOMIC_ACQUIRE, "agent");  // fallback
                __builtin_amdgcn_s_sleep(1);
#pragma unroll
                for (int j = 0; j < 16; ++j) SLOADC(tw[j], lb, j * 256);
                asm volatile("s_waitcnt vmcnt(0)" ::: "memory");
                __builtin_amdgcn_sched_barrier(0);
            }
        }

        // ==== LN partial stats of row lrow ====
        float s1 = 0.f, s2 = 0.f;
#pragma unroll
        for (int j = 0; j < 16; ++j) {
#pragma unroll
            for (int k = 0; k < 4; ++k) {
                const float v = __uint_as_float(tw[j][k] << 16);
                s1 += v;
                s2 = fmaf(v, v, s2);
            }
        }
        s1 += __shfl_xor(s1, 1); s2 += __shfl_xor(s2, 1);
        s1 += __shfl_xor(s1, 2); s2 += __shfl_xor(s2, 2);
        s1 += __shfl_xor(s1, 4); s2 += __shfl_xor(s2, 4);
        s1 += __shfl_xor(s1, 8); s2 += __shfl_xor(s2, 8);
        const float mu_l = s1 * (1.f / (float)H_);
        const float rs_l = rsqrtf(s2 * (1.f / (float)H_) - mu_l * mu_l + 1e-5f);

        // ==== repack to bf16 pairs, share via swizzled LDS ====
#pragma unroll
        for (int j = 0; j < 16; ++j) {
            const unsigned p0 = __builtin_amdgcn_perm(tw[j][1], tw[j][0], 0x05040100u);
            const unsigned p1 = __builtin_amdgcn_perm(tw[j][3], tw[j][2], 0x05040100u);
            const int idx = (j * 32 + c * 2) ^ swzW;
            *(uint2*)&Sl[lrow * 512 + idx] = uint2{p0, p1};
        }
        __syncthreads();   // (B)

        // ==== MFMA from LDS: acc = s_t @ Wslice^T ====
        f32x4 a0 = {0.f, 0.f, 0.f, 0.f}, a1 = a0, a2 = a0, a3 = a0;
#pragma unroll
        for (int kk = 0; kk < 32; kk += 4) {
#pragma unroll
            for (int q = 0; q < 4; ++q) {
                const int ai = ((kk + q) * 16 + rgrp * 4) ^ swzR;
                const uint32x4 aw = *(const uint32x4*)&Sl[c * 512 + ai];
                const bf16x8 af = __builtin_bit_cast(bf16x8, aw);
                const bf16x8 bf = *(const bf16x8*)(Wl +
                    ((size_t)((kk + q) * 4 + rgrp) * 64 + wave * 16 + c) * 8);
                if (q == 0) a0 = __builtin_amdgcn_mfma_f32_16x16x32_bf16(af, bf, a0, 0, 0, 0);
                if (q == 1) a1 = __builtin_amdgcn_mfma_f32_16x16x32_bf16(af, bf, a1, 0, 0, 0);
                if (q == 2) a2 = __builtin_amdgcn_mfma_f32_16x16x32_bf16(af, bf, a2, 0, 0, 0);
                if (q == 3) a3 = __builtin_amdgcn_mfma_f32_16x16x32_bf16(af, bf, a3, 0, 0, 0);
            }
        }
        const f32x4 acc = (a0 + a1) + (a2 + a3);

        // ==== update + publish tagged state (relaxed agent stores) ====
        float sprev[4];
#pragma unroll
        for (int r = 0; r < 4; ++r) {
            sprev[r] = sold[r];
            const float pre = acc[r] + uu[r] + bs_c;
            const float sn  = d_c * sold[r] + od_c * fast_tanh(pre);
            sold[r] = sn;
            __hip_atomic_store(&Sw[(size_t)(rgrp * 4 + r) * 1024 + mycol],
                               (tagw << 16) | f2bf_bits(sn),
                               __ATOMIC_RELAXED, __HIP_MEMORY_SCOPE_AGENT);
        }

        // ==== SPECULATIVE EARLY ISSUE for step t+1 (hidden under shadow) ====
        if (t + 1 < T_) {
#pragma unroll
            for (int r = 0; r < 4; ++r) {
                const float* ub = UY + ((size_t)brow[r] * T_ + (t + 1)) * H_ + mycol;
                ULOAD(uun[r], ub);
            }
            const unsigned* lbn =
                Sg + ((size_t)((t + 1) % 3) << 14) + (size_t)lrow * 1024 + c * 4;
#pragma unroll
            for (int j = 0; j < 16; ++j) SLOADC(tw[j], lbn, j * 256);
        }

        // ==== shadow: stats exchange, y_{t-2} store, yv = y_{t-1} ====
        __syncthreads();   // (C) MFMA Sl reads done (muS overlays Sl)
        if (c == 0) { muS[lrow] = mu_l; rsS[lrow] = rs_l; }
        __syncthreads();   // (D)
        if (t >= 2) {
#pragma unroll
            for (int r = 0; r < 4; ++r)
                UY[((size_t)brow[r] * T_ + (t - 2)) * H_ + mycol] = yv[r];
        }
        if (t > 0) {
#pragma unroll
            for (int r = 0; r < 4; ++r) {
                const int R = rgrp * 4 + r;
                yv[r] = (sprev[r] - muS[R]) * rsS[R] * g_c + be_c;
            }
        }
    }

    // ==== epilogue: store y_510 (yv), then y_511 = LN(s_512) ====
    {
#pragma unroll
        for (int r = 0; r < 4; ++r)
            UY[((size_t)brow[r] * T_ + (T_ - 2)) * H_ + mycol] = yv[r];

        const unsigned* Sr = Sg + ((size_t)(T_ % 3) << 14);
        const unsigned tagr = (unsigned)T_;
        const unsigned* lb = Sr + (size_t)lrow * 1024 + c * 4;
        uint32x4 tw2[16];
        int spin = 0;
#pragma unroll
        for (int j = 0; j < 16; ++j) SLOADC(tw2[j], lb, j * 256);
        for (;;) {
            asm volatile("s_waitcnt vmcnt(0)" ::: "memory");
            __builtin_amdgcn_sched_barrier(0);
            unsigned mn = 0xFFFFFFFFu;
#pragma unroll
            for (int j = 0; j < 16; ++j) {
                unsigned m01 = tw2[j][0] < tw2[j][1] ? tw2[j][0] : tw2[j][1];
                unsigned m23 = tw2[j][2] < tw2[j][3] ? tw2[j][2] : tw2[j][3];
                unsigned m = m01 < m23 ? m01 : m23;
                mn = mn < m ? mn : m;
            }
            if (__all((mn >> 16) == tagr)) break;
            if (((++spin) & 7) == 7)
                __builtin_amdgcn_fence(__ATOMIC_ACQUIRE, "agent");
            __builtin_amdgcn_s_sleep(1);
#pragma unroll
            for (int j = 0; j < 16; ++j) SLOADC(tw2[j], lb, j * 256);
        }
        float s1 = 0.f, s2 = 0.f;
#pragma unroll
        for (int j = 0; j < 16; ++j) {
#pragma unroll
            for (int k = 0; k < 4; ++k) {
                const float v = __uint_as_float(tw2[j][k] << 16);
                s1 += v;
                s2 = fmaf(v, v, s2);
            }
        }
        s1 += __shfl_xor(s1, 1); s2 += __shfl_xor(s2, 1);
        s1 += __shfl_xor(s1, 2); s2 += __shfl_xor(s2, 2);
        s1 += __shfl_xor(s1, 4); s2 += __shfl_xor(s2, 4);
        s1 += __shfl_xor(s1, 8); s2 += __shfl_xor(s2, 8);
        const float mu_l = s1 * (1.f / (float)H_);
        const float rs_l = rsqrtf(s2 * (1.f / (float)H_) - mu_l * mu_l + 1e-5f);
        __syncthreads();                      // last yv reads of muS done
        if (c == 0) { muS[lrow] = mu_l; rsS[lrow] = rs_l; }
        __syncthreads();
#pragma unroll
        for (int r = 0; r < 4; ++r) {
            const int R = rgrp * 4 + r;
            UY[((size_t)brow[r] * T_ + (T_ - 1)) * H_ + mycol] =
                (sold[r] - muS[R]) * rsS[R] * g_c + be_c;
        }
    }
}

// ---------------------------------------------------------------------------
extern "C" void kernel_launch(void* const* d_in, const int* in_sizes, int n_in,
                              void* d_out, int out_size, void* d_ws, size_t ws_size,
                              hipStream_t stream) {
    const float* x   = (const float*)d_in[0];
    const float* Win = (const float*)d_in[1];
    const float* bin = (const float*)d_in[2];
    const float* Wst = (const float*)d_in[3];
    const float* bst = (const float*)d_in[4];
    const float* dec = (const float*)d_in[5];
    const float* lng = (const float*)d_in[6];
    const float* lnb = (const float*)d_in[7];
    float* out = (float*)d_out;

    unsigned char* ws = (unsigned char*)d_ws;
    unsigned* Sbuf = (unsigned*)(ws + 4096);     // 4 groups x 3 parities x 64KB

    hipFuncSetAttribute(reinterpret_cast<const void*>(rec_tag3),
                        hipFuncAttributeMaxDynamicSharedMemorySize, 163840);

    hipMemsetAsync(Sbuf, 0, 4u * 3u * 16u * 1024u * 4u, stream);  // tag0 = s_0
    u_gemm<<<dim3(8, 256), 256, 0, stream>>>(x, Win, bin, out);
    rec_tag3<<<64, 256, 163840, stream>>>(Wst, out, bst, dec, lng, lnb, Sbuf);
}